// Round 1
// baseline (129.607 us; speedup 1.0000x reference)
//
#include <hip/hip_runtime.h>
#include <hip/hip_bf16.h>

typedef unsigned short u16;
typedef __bf16 bf16x8 __attribute__((ext_vector_type(8)));
typedef float f32x4 __attribute__((ext_vector_type(4)));

#define SEQ 2048
#define DH  64
// ws layout: qT [32][2048][64] bf16 | kT [32][2048][64] bf16 | v [32][64][2048] bf16 = 24 MB

__device__ __forceinline__ u16 f2bf(float x) {
  __bf16 h = (__bf16)x;
  return __builtin_bit_cast(u16, h);
}

// ---- pre-pass 1: transpose q,k -> [bh][t][c] bf16 (q scaled by 1/8) ----
__global__ __launch_bounds__(256) void transpose_qk(const float* __restrict__ qkv,
                                                    u16* __restrict__ qT,
                                                    u16* __restrict__ kT) {
  int idx = blockIdx.x;            // [0, 2048): which(2) x bh(32) x ttile(32)
  int which = idx >> 10;           // 0=q, 1=k
  int bh = (idx >> 5) & 31;
  int t0 = (idx & 31) * 64;
  int b = bh >> 3, h = bh & 7;
  const float* src = qkv + ((size_t)(b*1536 + which*512 + h*64)) * SEQ;
  u16* dst = (which ? kT : qT) + (size_t)bh * SEQ * DH;
  float scale = which ? 1.0f : 0.125f;

  __shared__ float tile[64][65];
  int tl = threadIdx.x & 63;
  int cw = threadIdx.x >> 6;
#pragma unroll
  for (int i = 0; i < 16; ++i) {
    int c = cw + 4*i;
    tile[c][tl] = src[(size_t)c*SEQ + t0 + tl] * scale;
  }
  __syncthreads();
  int cl2 = (threadIdx.x & 31) * 2;
  int tw  = threadIdx.x >> 5;
#pragma unroll
  for (int i = 0; i < 8; ++i) {
    int t = tw + 8*i;
    unsigned int lo = f2bf(tile[cl2][t]);
    unsigned int hi = f2bf(tile[cl2+1][t]);
    *(unsigned int*)(dst + (size_t)(t0 + t)*DH + cl2) = lo | (hi << 16);
  }
}

// ---- pre-pass 2: v -> bf16, native [bh][c][s] layout ----
__global__ __launch_bounds__(256) void convert_v(const float* __restrict__ qkv,
                                                 u16* __restrict__ v) {
  int row = blockIdx.x;            // bh*64 + c
  int bh = row >> 6, c = row & 63;
  int b = bh >> 3, h = bh & 7;
  const float4* src = (const float4*)(qkv + ((size_t)(b*1536 + 1024 + h*64 + c)) * SEQ);
  u16* dst = v + (size_t)row * SEQ;
  int tid = threadIdx.x;
  float4 a = src[tid*2];
  float4 bq = src[tid*2+1];
  union { u16 u[8]; int4 v4; } pk;
  pk.u[0]=f2bf(a.x); pk.u[1]=f2bf(a.y); pk.u[2]=f2bf(a.z); pk.u[3]=f2bf(a.w);
  pk.u[4]=f2bf(bq.x); pk.u[5]=f2bf(bq.y); pk.u[6]=f2bf(bq.z); pk.u[7]=f2bf(bq.w);
  *(int4*)(dst + tid*8) = pk.v4;
}

// ---- flash attention: 1 block = (head, 64 q-rows); wave = 16 q-rows ----
__global__ __launch_bounds__(256) void attn(const u16* __restrict__ qT,
                                            const u16* __restrict__ kT,
                                            const u16* __restrict__ vB,
                                            float* __restrict__ out) {
  const int bh = blockIdx.x >> 5;
  const int t0 = (blockIdx.x & 31) * 64;
  const int tid  = threadIdx.x;
  const int wave = tid >> 6;
  const int lane = tid & 63;
  const int l15  = lane & 15;
  const int g    = lane >> 4;

  // rows are 64 bf16 = 8 chunks of 16B; chunk index XOR (row&7) kills bank conflicts
  __shared__ __align__(16) u16 kbuf[64*64];     // [s][c] swizzled
  __shared__ __align__(16) u16 vbuf[64*64];     // [c][s] swizzled
  __shared__ __align__(16) u16 pbuf[4][16*64];  // per wave: [t][s] swizzled
  __shared__ float sbuf[4][16];

  // Q fragment (A of QK): A[m=t][k=c], m=l15, k=8g+j ; reused for all s
  const u16* qrow = qT + ((size_t)bh*SEQ + (t0 + wave*16 + l15)) * DH;
  const bf16x8 aq0 = *(const bf16x8*)(qrow + g*8);        // c in [0,32)
  const bf16x8 aq1 = *(const bf16x8*)(qrow + 32 + g*8);   // c in [32,64)

  const f32x4 zero4 = {0.f, 0.f, 0.f, 0.f};
  f32x4 acc[4];   // D[c][t]: c = 16*ct + 4g + r, t = t0+16*wave+l15
#pragma unroll
  for (int i = 0; i < 4; ++i) acc[i] = zero4;
  float m_run[4], l_run[4];
#pragma unroll
  for (int r = 0; r < 4; ++r) { m_run[r] = -1e30f; l_run[r] = 0.f; }

  const u16* ksrc0 = kT + (size_t)bh*SEQ*DH;
  const u16* vsrc0 = vB + (size_t)bh*DH*SEQ;
  u16* pw = pbuf[wave];

  for (int s0 = 0; s0 < SEQ; s0 += 64) {
    __syncthreads();
    { // stage K tile [64s][64c] and V tile [64c][64s], swizzled
      int row = tid >> 2;
      int k0  = (tid & 3) * 2;
      const int4* ks = (const int4*)(ksrc0 + (size_t)s0*DH + tid*16);
      int4 kd0 = ks[0], kd1 = ks[1];
      *(int4*)(kbuf + row*64 + (((k0  ) ^ (row & 7)) * 8)) = kd0;
      *(int4*)(kbuf + row*64 + (((k0+1) ^ (row & 7)) * 8)) = kd1;
      const u16* vs = vsrc0 + (size_t)row*SEQ + s0 + k0*8;
      int4 vd0 = *(const int4*)vs;
      int4 vd1 = *(const int4*)(vs + 8);
      *(int4*)(vbuf + row*64 + (((k0  ) ^ (row & 7)) * 8)) = vd0;
      *(int4*)(vbuf + row*64 + (((k0+1) ^ (row & 7)) * 8)) = vd1;
    }
    __syncthreads();

    // QK^T: S[t][s], 4 s-subtiles of 16
    f32x4 S[4];
#pragma unroll
    for (int st = 0; st < 4; ++st) {
      int srow = st*16 + l15;
      bf16x8 b0 = *(const bf16x8*)(kbuf + srow*64 + (((g  ) ^ (srow & 7)) * 8));
      bf16x8 b1 = *(const bf16x8*)(kbuf + srow*64 + (((g+4) ^ (srow & 7)) * 8));
      f32x4 z = zero4;
      z = __builtin_amdgcn_mfma_f32_16x16x32_bf16(aq0, b0, z, 0, 0, 0);
      z = __builtin_amdgcn_mfma_f32_16x16x32_bf16(aq1, b1, z, 0, 0, 0);
      S[st] = z;  // lane: t_local = 4g+r, s_local = 16*st + l15
    }

    // online softmax over s
    float m_new[4], alpha[4], ls[4];
#pragma unroll
    for (int r = 0; r < 4; ++r) {
      float v0 = fmaxf(fmaxf(S[0][r], S[1][r]), fmaxf(S[2][r], S[3][r]));
#pragma unroll
      for (int d = 1; d < 16; d <<= 1) v0 = fmaxf(v0, __shfl_xor(v0, d));
      m_new[r] = fmaxf(m_run[r], v0);
      alpha[r] = __expf(m_run[r] - m_new[r]);
      ls[r] = 0.f;
    }
#pragma unroll
    for (int st = 0; st < 4; ++st) {
      int slo = st*16 + l15;
      int schunk = slo >> 3;
      int sbyte  = slo & 7;
#pragma unroll
      for (int r = 0; r < 4; ++r) {
        float p = __expf(S[st][r] - m_new[r]);
        ls[r] += p;
        int trow = g*4 + r;
        pw[trow*64 + ((schunk ^ (trow & 7)) * 8) + sbyte] = f2bf(p);
      }
    }
#pragma unroll
    for (int r = 0; r < 4; ++r) {
      float v0 = ls[r];
#pragma unroll
      for (int d = 1; d < 16; d <<= 1) v0 += __shfl_xor(v0, d);
      l_run[r] = l_run[r] * alpha[r] + v0;
      m_run[r] = m_new[r];
    }
    if (l15 == 0) {
#pragma unroll
      for (int r = 0; r < 4; ++r) sbuf[wave][g*4 + r] = alpha[r];
    }
    __syncthreads();  // settle pbuf + sbuf (also cross-lane broadcast)

    float arf = sbuf[wave][l15];
#pragma unroll
    for (int ct = 0; ct < 4; ++ct)
#pragma unroll
      for (int r = 0; r < 4; ++r) acc[ct][r] *= arf;

    // PV: D[c][t] += V[c][s] * P^T[s][t]
    bf16x8 p0 = *(const bf16x8*)(pw + l15*64 + (((g  ) ^ (l15 & 7)) * 8));
    bf16x8 p1 = *(const bf16x8*)(pw + l15*64 + (((g+4) ^ (l15 & 7)) * 8));
#pragma unroll
    for (int ct = 0; ct < 4; ++ct) {
      int vr = ct*16 + l15;
      bf16x8 v0 = *(const bf16x8*)(vbuf + vr*64 + (((g  ) ^ (vr & 7)) * 8));
      bf16x8 v1 = *(const bf16x8*)(vbuf + vr*64 + (((g+4) ^ (vr & 7)) * 8));
      acc[ct] = __builtin_amdgcn_mfma_f32_16x16x32_bf16(v0, p0, acc[ct], 0, 0, 0);
      acc[ct] = __builtin_amdgcn_mfma_f32_16x16x32_bf16(v1, p1, acc[ct], 0, 0, 0);
    }
  }

  // epilogue: broadcast l, normalize, store out[bh*64+c][t]
  __syncthreads();
  if (l15 == 0) {
#pragma unroll
    for (int r = 0; r < 4; ++r) sbuf[wave][g*4 + r] = l_run[r];
  }
  __syncthreads();
  float linv = 1.0f / sbuf[wave][l15];
  float* ob = out + (size_t)(bh*64) * SEQ + t0 + wave*16 + l15;
#pragma unroll
  for (int ct = 0; ct < 4; ++ct)
#pragma unroll
    for (int r = 0; r < 4; ++r)
      ob[(size_t)(ct*16 + g*4 + r) * SEQ] = acc[ct][r] * linv;
}

extern "C" void kernel_launch(void* const* d_in, const int* in_sizes, int n_in,
                              void* d_out, int out_size, void* d_ws, size_t ws_size,
                              hipStream_t stream) {
  const float* qkv = (const float*)d_in[0];
  float* out = (float*)d_out;
  u16* qT = (u16*)d_ws;
  u16* kT = qT + (size_t)32*SEQ*DH;
  u16* vB = kT + (size_t)32*SEQ*DH;
  transpose_qk<<<2048, 256, 0, stream>>>(qkv, qT, kT);
  convert_v<<<2048, 256, 0, stream>>>(qkv, vB);
  attn<<<1024, 256, 0, stream>>>(qT, kT, vB, out);
}

// Round 2
// 86.914 us; speedup vs baseline: 1.4912x; 1.4912x over previous
//
#include <hip/hip_runtime.h>
#include <hip/hip_bf16.h>

typedef unsigned short u16;
typedef __bf16 bf16x8 __attribute__((ext_vector_type(8)));
typedef float f32x4 __attribute__((ext_vector_type(4)));

#define SEQ 2048
#define DH  64
// ws layout: qT [32][2048][64] bf16 | kT [32][2048][64] bf16 | v [32][64][2048] bf16 = 24 MB

__device__ __forceinline__ u16 f2bf(float x) {
  __bf16 h = (__bf16)x;
  return __builtin_bit_cast(u16, h);
}

// ---- pre-pass 1: transpose q,k -> [bh][t][c] bf16 (q scaled by 1/8) ----
__global__ __launch_bounds__(256) void transpose_qk(const float* __restrict__ qkv,
                                                    u16* __restrict__ qT,
                                                    u16* __restrict__ kT) {
  int idx = blockIdx.x;            // [0, 2048): which(2) x bh(32) x ttile(32)
  int which = idx >> 10;           // 0=q, 1=k
  int bh = (idx >> 5) & 31;
  int t0 = (idx & 31) * 64;
  int b = bh >> 3, h = bh & 7;
  const float* src = qkv + ((size_t)(b*1536 + which*512 + h*64)) * SEQ;
  u16* dst = (which ? kT : qT) + (size_t)bh * SEQ * DH;
  float scale = which ? 1.0f : 0.125f;

  __shared__ float tile[64][65];
  int tl = threadIdx.x & 63;
  int cw = threadIdx.x >> 6;
#pragma unroll
  for (int i = 0; i < 16; ++i) {
    int c = cw + 4*i;
    tile[c][tl] = src[(size_t)c*SEQ + t0 + tl] * scale;
  }
  __syncthreads();
  int cl2 = (threadIdx.x & 31) * 2;
  int tw  = threadIdx.x >> 5;
#pragma unroll
  for (int i = 0; i < 8; ++i) {
    int t = tw + 8*i;
    unsigned int lo = f2bf(tile[cl2][t]);
    unsigned int hi = f2bf(tile[cl2+1][t]);
    *(unsigned int*)(dst + (size_t)(t0 + t)*DH + cl2) = lo | (hi << 16);
  }
}

// ---- pre-pass 2: v -> bf16, native [bh][c][s] layout ----
__global__ __launch_bounds__(256) void convert_v(const float* __restrict__ qkv,
                                                 u16* __restrict__ v) {
  int row = blockIdx.x;            // bh*64 + c
  int bh = row >> 6, c = row & 63;
  int b = bh >> 3, h = bh & 7;
  const float4* src = (const float4*)(qkv + ((size_t)(b*1536 + 1024 + h*64 + c)) * SEQ);
  u16* dst = v + (size_t)row * SEQ;
  int tid = threadIdx.x;
  float4 a = src[tid*2];
  float4 bq = src[tid*2+1];
  union { u16 u[8]; int4 v4; } pk;
  pk.u[0]=f2bf(a.x); pk.u[1]=f2bf(a.y); pk.u[2]=f2bf(a.z); pk.u[3]=f2bf(a.w);
  pk.u[4]=f2bf(bq.x); pk.u[5]=f2bf(bq.y); pk.u[6]=f2bf(bq.z); pk.u[7]=f2bf(bq.w);
  *(int4*)(dst + tid*8) = pk.v4;
}

// ---- flash attention, swapped-QK layout ----
// block = (head, 64 q-rows), wave = 16 q-rows. S^T = mfma(K,Q): lane (g,l15)
// holds S^T[s=16st+4g+r][t=l15] -> softmax stats are lane-local in t, matching
// PV acc D[c=16ct+4g+r][t=l15]. One barrier per s-tile; dbuf'd global_load_lds
// staging with pre-swizzled global source (linear LDS dest).
__global__ __launch_bounds__(256) void attn(const u16* __restrict__ qT,
                                            const u16* __restrict__ kT,
                                            const u16* __restrict__ vB,
                                            float* __restrict__ out) {
  const int bh = blockIdx.x >> 5;
  const int t0 = (blockIdx.x & 31) * 64;
  const int tid  = threadIdx.x;
  const int wave = tid >> 6;
  const int lane = tid & 63;
  const int l15  = lane & 15;
  const int g    = lane >> 4;

  // K/V tiles: [row][8 chunks of 16B], LDS chunk ch holds global chunk ch^(row&7)
  __shared__ __align__(16) u16 kbuf[2][64*64];   // [s][c]
  __shared__ __align__(16) u16 vbuf[2][64*64];   // [c][s]
  __shared__ __align__(16) u16 pbuf[4][16*64];   // per-wave P^T bounce [t][s]

  // Q fragment (B of QK^T): B[k=c][n=t], n=l15 -> t, k=8g+j
  const u16* qrow = qT + ((size_t)bh*SEQ + (t0 + wave*16 + l15)) * DH;
  const bf16x8 bq0 = *(const bf16x8*)(qrow + g*8);        // c in [0,32)
  const bf16x8 bq1 = *(const bf16x8*)(qrow + 32 + g*8);   // c in [32,64)

  // staging: 4 global_load_lds x16B per wave per tile (2 K segs + 2 V segs)
  const u16* ksrc0 = kT + (size_t)bh*SEQ*DH;
  const u16* vsrc0 = vB + (size_t)bh*DH*SEQ;
  const int ci0 = (wave*2+0)*64 + lane;   // chunk index 0..511
  const int ci1 = (wave*2+1)*64 + lane;
  const int kr0 = ci0 >> 3, kc0 = ci0 & 7;
  const int kr1 = ci1 >> 3, kc1 = ci1 & 7;
  const u16* kg0 = ksrc0 + (size_t)kr0*DH + ((kc0 ^ (kr0 & 7)) * 8);
  const u16* kg1 = ksrc0 + (size_t)kr1*DH + ((kc1 ^ (kr1 & 7)) * 8);
  const u16* vg0 = vsrc0 + (size_t)kr0*SEQ + ((kc0 ^ (kr0 & 7)) * 8);
  const u16* vg1 = vsrc0 + (size_t)kr1*SEQ + ((kc1 ^ (kr1 & 7)) * 8);

#define STAGE(b, s0) do {                                                         \
    __builtin_amdgcn_global_load_lds(                                             \
      (const __attribute__((address_space(1))) unsigned int*)(kg0 + (size_t)(s0)*DH), \
      (__attribute__((address_space(3))) unsigned int*)(&kbuf[b][(wave*2+0)*512]), 16, 0, 0); \
    __builtin_amdgcn_global_load_lds(                                             \
      (const __attribute__((address_space(1))) unsigned int*)(kg1 + (size_t)(s0)*DH), \
      (__attribute__((address_space(3))) unsigned int*)(&kbuf[b][(wave*2+1)*512]), 16, 0, 0); \
    __builtin_amdgcn_global_load_lds(                                             \
      (const __attribute__((address_space(1))) unsigned int*)(vg0 + (s0)),        \
      (__attribute__((address_space(3))) unsigned int*)(&vbuf[b][(wave*2+0)*512]), 16, 0, 0); \
    __builtin_amdgcn_global_load_lds(                                             \
      (const __attribute__((address_space(1))) unsigned int*)(vg1 + (s0)),        \
      (__attribute__((address_space(3))) unsigned int*)(&vbuf[b][(wave*2+1)*512]), 16, 0, 0); \
  } while (0)

  const f32x4 zero4 = {0.f, 0.f, 0.f, 0.f};
  f32x4 acc[4];   // D[c][t]: c = 16ct+4g+r, t = t0+16w+l15
#pragma unroll
  for (int i = 0; i < 4; ++i) acc[i] = zero4;
  float m_run = -3.0e38f, l_run = 0.f;

  u16* pw = pbuf[wave];

  STAGE(0, 0);
  __syncthreads();

  int buf = 0;
  for (int s0 = 0; s0 < SEQ; s0 += 64) {
    if (s0 + 64 < SEQ) STAGE(buf ^ 1, s0 + 64);   // async prefetch next tile

    // QK^T swapped: S^T = K * Q. A = K-frag (m=s), B = Q-frag (n=t).
    const u16* kb = kbuf[buf];
    f32x4 S[4];
#pragma unroll
    for (int st = 0; st < 4; ++st) {
      int srow = st*16 + l15;
      bf16x8 a0 = *(const bf16x8*)(kb + srow*64 + (((g  ) ^ (srow & 7)) * 8));
      bf16x8 a1 = *(const bf16x8*)(kb + srow*64 + (((g+4) ^ (srow & 7)) * 8));
      f32x4 z = zero4;
      z = __builtin_amdgcn_mfma_f32_16x16x32_bf16(a0, bq0, z, 0, 0, 0);
      z = __builtin_amdgcn_mfma_f32_16x16x32_bf16(a1, bq1, z, 0, 0, 0);
      S[st] = z;  // S^T[s=16st+4g+r][t=l15]
    }

    // online softmax: all stats lane-local in t; reduce over s = local + 2 shfl
    float vmax = S[0][0];
#pragma unroll
    for (int st = 0; st < 4; ++st)
#pragma unroll
      for (int r = 0; r < 4; ++r) vmax = fmaxf(vmax, S[st][r]);
    vmax = fmaxf(vmax, __shfl_xor(vmax, 16));
    vmax = fmaxf(vmax, __shfl_xor(vmax, 32));
    float m_new = fmaxf(m_run, vmax);
    float alpha = __expf(m_run - m_new);
    float ls = 0.f;
#pragma unroll
    for (int st = 0; st < 4; ++st) {
      union { u16 u[4]; unsigned long long q; } pk;
#pragma unroll
      for (int r = 0; r < 4; ++r) {
        float p = __expf(S[st][r] - m_new);
        ls += p;
        pk.u[r] = f2bf(p);
      }
      // P^T[s=16st+4g+r][t=l15] -> pbuf[t][s], 16B-chunk XOR swizzle
      *(unsigned long long*)((char*)pw + l15*128 +
          (((2*st + (g >> 1)) ^ (l15 & 7)) * 16) + (g & 1) * 8) = pk.q;
    }
    ls += __shfl_xor(ls, 16);
    ls += __shfl_xor(ls, 32);
    l_run = l_run * alpha + ls;
    m_run = m_new;

#pragma unroll
    for (int ct = 0; ct < 4; ++ct)
#pragma unroll
      for (int r = 0; r < 4; ++r) acc[ct][r] *= alpha;

    // P fragments for PV (same-wave LDS RAW, ordered by lgkmcnt — no barrier)
    bf16x8 p0 = *(const bf16x8*)((char*)pw + l15*128 + (((g  ) ^ (l15 & 7)) * 16));
    bf16x8 p1 = *(const bf16x8*)((char*)pw + l15*128 + (((4+g) ^ (l15 & 7)) * 16));

    // PV: D[c][t] += V[c][s] * P^T[s][t]
    const u16* vb = vbuf[buf];
#pragma unroll
    for (int ct = 0; ct < 4; ++ct) {
      int vr = ct*16 + l15;
      bf16x8 v0 = *(const bf16x8*)(vb + vr*64 + (((g  ) ^ (vr & 7)) * 8));
      bf16x8 v1 = *(const bf16x8*)(vb + vr*64 + (((g+4) ^ (vr & 7)) * 8));
      acc[ct] = __builtin_amdgcn_mfma_f32_16x16x32_bf16(v0, p0, acc[ct], 0, 0, 0);
      acc[ct] = __builtin_amdgcn_mfma_f32_16x16x32_bf16(v1, p1, acc[ct], 0, 0, 0);
    }

    __syncthreads();   // waves done reading buf; prefetch into buf^1 has landed
    buf ^= 1;
  }
#undef STAGE

  float linv = 1.0f / l_run;
  float* ob = out + (size_t)(bh*64) * SEQ + t0 + wave*16 + l15;
#pragma unroll
  for (int ct = 0; ct < 4; ++ct)
#pragma unroll
    for (int r = 0; r < 4; ++r)
      ob[(size_t)(ct*16 + 4*g + r) * SEQ] = acc[ct][r] * linv;
}

extern "C" void kernel_launch(void* const* d_in, const int* in_sizes, int n_in,
                              void* d_out, int out_size, void* d_ws, size_t ws_size,
                              hipStream_t stream) {
  const float* qkv = (const float*)d_in[0];
  float* out = (float*)d_out;
  u16* qT = (u16*)d_ws;
  u16* kT = qT + (size_t)32*SEQ*DH;
  u16* vB = kT + (size_t)32*SEQ*DH;
  transpose_qk<<<2048, 256, 0, stream>>>(qkv, qT, kT);
  convert_v<<<2048, 256, 0, stream>>>(qkv, vB);
  attn<<<1024, 256, 0, stream>>>(qT, kT, vB, out);
}

// Round 4
// 74.475 us; speedup vs baseline: 1.7403x; 1.1670x over previous
//
#include <hip/hip_runtime.h>
#include <hip/hip_bf16.h>

typedef unsigned short u16;
typedef unsigned int uint;
typedef __bf16 bf16x8 __attribute__((ext_vector_type(8)));
typedef float f32x16 __attribute__((ext_vector_type(16)));

#define SEQ 2048
#define DH  64
// ws: qT [32][2048][64] bf16 | kT [32][2048][64] bf16 | v [32][64][2048] bf16

__device__ __forceinline__ u16 f2bf(float x) {
  __bf16 h = (__bf16)x;
  return __builtin_bit_cast(u16, h);
}

// ---- pre-pass 1: transpose q,k -> [bh][t][c] bf16 (q scaled by log2e/8) ----
__global__ __launch_bounds__(256) void transpose_qk(const float* __restrict__ qkv,
                                                    u16* __restrict__ qT,
                                                    u16* __restrict__ kT) {
  int idx = blockIdx.x;            // which(2) x bh(32) x ttile(32)
  int which = idx >> 10;
  int bh = (idx >> 5) & 31;
  int t0 = (idx & 31) * 64;
  int b = bh >> 3, h = bh & 7;
  const float* src = qkv + ((size_t)(b*1536 + which*512 + h*64)) * SEQ;
  u16* dst = (which ? kT : qT) + (size_t)bh * SEQ * DH;
  float scale = which ? 1.0f : 0.1803368801111244f;   // 0.125 * log2(e)

  __shared__ float tile[64][65];
  int tl = threadIdx.x & 63;
  int cw = threadIdx.x >> 6;
#pragma unroll
  for (int i = 0; i < 16; ++i) {
    int c = cw + 4*i;
    tile[c][tl] = src[(size_t)c*SEQ + t0 + tl] * scale;
  }
  __syncthreads();
  int cl2 = (threadIdx.x & 31) * 2;
  int tw  = threadIdx.x >> 5;
#pragma unroll
  for (int i = 0; i < 8; ++i) {
    int t = tw + 8*i;
    unsigned int lo = f2bf(tile[cl2][t]);
    unsigned int hi = f2bf(tile[cl2+1][t]);
    *(unsigned int*)(dst + (size_t)(t0 + t)*DH + cl2) = lo | (hi << 16);
  }
}

// ---- pre-pass 2: v -> bf16, native [bh][c][s] layout ----
__global__ __launch_bounds__(256) void convert_v(const float* __restrict__ qkv,
                                                 u16* __restrict__ v) {
  int row = blockIdx.x;            // bh*64 + c
  int bh = row >> 6, c = row & 63;
  int b = bh >> 3, h = bh & 7;
  const float4* src = (const float4*)(qkv + ((size_t)(b*1536 + 1024 + h*64 + c)) * SEQ);
  u16* dst = v + (size_t)row * SEQ;
  int tid = threadIdx.x;
  float4 a = src[tid*2];
  float4 bq = src[tid*2+1];
  union { u16 u[8]; int4 v4; } pk;
  pk.u[0]=f2bf(a.x); pk.u[1]=f2bf(a.y); pk.u[2]=f2bf(a.z); pk.u[3]=f2bf(a.w);
  pk.u[4]=f2bf(bq.x); pk.u[5]=f2bf(bq.y); pk.u[6]=f2bf(bq.z); pk.u[7]=f2bf(bq.w);
  *(int4*)(dst + tid*8) = pk.v4;
}

// ---- flash attention: 32x32x16 MFMA, 32 q-rows/wave, in-register P ----
// S^T = mfma32(K,Q): lane(l31,hi) holds col t=l31, rows s=(r&3)+8(r>>2)+4hi
// per 32-s tile. Softmax lane-local + 1 shfl_xor(32). P -> PV B-frag via
// 16 cvt_pk + 8 permlane32_swap (no LDS bounce). log2-domain exp2, defer-max.
__global__ __launch_bounds__(256) void attn(const u16* __restrict__ qT,
                                            const u16* __restrict__ kT,
                                            const u16* __restrict__ vB,
                                            float* __restrict__ out) {
  // XCD-bijective swizzle (512 blocks, 512%8==0): heads stay L2-local per XCD
  const int lb = (blockIdx.x & 7) * 64 + (blockIdx.x >> 3);
  const int bh = lb >> 4;           // 16 t-tiles (of 128) per head
  const int t0 = (lb & 15) * 128;
  const int tid  = threadIdx.x;
  const int wave = tid >> 6;
  const int lane = tid & 63;
  const int l31  = lane & 31;
  const int hi   = lane >> 5;

  // K/V tiles [row][8 chunks of 16B]; LDS chunk ch holds global chunk ch^(row&7)
  __shared__ __align__(16) u16 kbuf[2][64*64];   // [s][c]
  __shared__ __align__(16) u16 vbuf[2][64*64];   // [c][s]

  // Q B-frags: n=t=l31, k=8hi+j, c = kb*16+8hi+j
  const u16* qrow = qT + ((size_t)bh*SEQ + (t0 + wave*32 + l31)) * DH;
  bf16x8 bq[4];
#pragma unroll
  for (int kb = 0; kb < 4; ++kb) bq[kb] = *(const bf16x8*)(qrow + kb*16 + hi*8);

  // staging: 4 global_load_lds x16B per wave per tile, pre-swizzled global src
  const u16* ksrc0 = kT + (size_t)bh*SEQ*DH;
  const u16* vsrc0 = vB + (size_t)bh*DH*SEQ;
  const int ci0 = (wave*2+0)*64 + lane;   // chunk 0..511
  const int ci1 = (wave*2+1)*64 + lane;
  const int kr0 = ci0 >> 3, kc0 = ci0 & 7;
  const int kr1 = ci1 >> 3, kc1 = ci1 & 7;
  const u16* kg0 = ksrc0 + (size_t)kr0*DH + ((kc0 ^ (kr0 & 7)) * 8);
  const u16* kg1 = ksrc0 + (size_t)kr1*DH + ((kc1 ^ (kr1 & 7)) * 8);
  const u16* vg0 = vsrc0 + (size_t)kr0*SEQ + ((kc0 ^ (kr0 & 7)) * 8);
  const u16* vg1 = vsrc0 + (size_t)kr1*SEQ + ((kc1 ^ (kr1 & 7)) * 8);

#define STAGE(b, s0) do {                                                         \
    __builtin_amdgcn_global_load_lds(                                             \
      (const __attribute__((address_space(1))) unsigned int*)(kg0 + (size_t)(s0)*DH), \
      (__attribute__((address_space(3))) unsigned int*)(&kbuf[b][(wave*2+0)*512]), 16, 0, 0); \
    __builtin_amdgcn_global_load_lds(                                             \
      (const __attribute__((address_space(1))) unsigned int*)(kg1 + (size_t)(s0)*DH), \
      (__attribute__((address_space(3))) unsigned int*)(&kbuf[b][(wave*2+1)*512]), 16, 0, 0); \
    __builtin_amdgcn_global_load_lds(                                             \
      (const __attribute__((address_space(1))) unsigned int*)(vg0 + (s0)),        \
      (__attribute__((address_space(3))) unsigned int*)(&vbuf[b][(wave*2+0)*512]), 16, 0, 0); \
    __builtin_amdgcn_global_load_lds(                                             \
      (const __attribute__((address_space(1))) unsigned int*)(vg1 + (s0)),        \
      (__attribute__((address_space(3))) unsigned int*)(&vbuf[b][(wave*2+1)*512]), 16, 0, 0); \
  } while (0)

  f32x16 acc0 = {}, acc1 = {};   // D[c][t]: t=l31, c=(r&3)+8(r>>2)+4hi (+32 for acc1)
  float m_run = -3.0e38f, l_run = 0.f;

  STAGE(0, 0);
  __syncthreads();

  int buf = 0;
  for (int s0 = 0; s0 < SEQ; s0 += 64) {
    if (s0 + 64 < SEQ) STAGE(buf ^ 1, s0 + 64);   // async prefetch next tile

    // QK^T swapped: S^T = K*Q. A-frag: m=s-row=l31, k=8hi+j.
    const u16* kb_ = kbuf[buf];
    f32x16 S0 = {}, S1 = {};
    __builtin_amdgcn_s_setprio(1);
#pragma unroll
    for (int kb = 0; kb < 4; ++kb) {
      bf16x8 a0 = *(const bf16x8*)(kb_ + l31*64      + (((2*kb+hi) ^ (l31 & 7)) * 8));
      bf16x8 a1 = *(const bf16x8*)(kb_ + (32+l31)*64 + (((2*kb+hi) ^ (l31 & 7)) * 8));
      S0 = __builtin_amdgcn_mfma_f32_32x32x16_bf16(a0, bq[kb], S0, 0, 0, 0);
      S1 = __builtin_amdgcn_mfma_f32_32x32x16_bf16(a1, bq[kb], S1, 0, 0, 0);
    }
    __builtin_amdgcn_s_setprio(0);

    // online softmax (log2 domain), stats lane-local in t
    float vmax = S0[0];
#pragma unroll
    for (int i = 1; i < 16; ++i) vmax = fmaxf(vmax, S0[i]);
#pragma unroll
    for (int i = 0; i < 16; ++i) vmax = fmaxf(vmax, S1[i]);
    vmax = fmaxf(vmax, __shfl_xor(vmax, 32));

    if (!__all(vmax - m_run <= 8.0f)) {    // defer-max: skip rescale when stable
      float m_new = fmaxf(m_run, vmax);
      float alpha = __builtin_amdgcn_exp2f(m_run - m_new);
      l_run *= alpha;
#pragma unroll
      for (int i = 0; i < 16; ++i) { acc0[i] *= alpha; acc1[i] *= alpha; }
      m_run = m_new;
    }

    float p0[16], p1[16];
    float ls = 0.f;
#pragma unroll
    for (int i = 0; i < 16; ++i) { p0[i] = __builtin_amdgcn_exp2f(S0[i] - m_run); ls += p0[i]; }
#pragma unroll
    for (int i = 0; i < 16; ++i) { p1[i] = __builtin_amdgcn_exp2f(S1[i] - m_run); ls += p1[i]; }
    ls += __shfl_xor(ls, 32);
    l_run += ls;

    // pack P to bf16 dwords: d[2q+e] = (p[4q+2e], p[4q+2e+1]) -> s = 8q+4hi+2e(+1)
    uint d0[8], d1[8];
#pragma unroll
    for (int q = 0; q < 4; ++q)
#pragma unroll
      for (int e = 0; e < 2; ++e) {
        asm("v_cvt_pk_bf16_f32 %0, %1, %2" : "=v"(d0[2*q+e]) : "v"(p0[4*q+2*e]), "v"(p0[4*q+2*e+1]));
        asm("v_cvt_pk_bf16_f32 %0, %1, %2" : "=v"(d1[2*q+e]) : "v"(p1[4*q+2*e]), "v"(p1[4*q+2*e+1]));
      }
    // swap(D=X, S=Y): new X[hi lanes] = lo-lane Y (s+8), new Y[lo lanes] = hi-lane X (s+4).
    // Result: X' = pf dword0/1 (s..s+3 per-lane), Y' = pf dword2/3 (s+4..s+7 per-lane).
    bf16x8 pf[4];
#pragma unroll
    for (int st2 = 0; st2 < 2; ++st2)
#pragma unroll
      for (int kb2 = 0; kb2 < 2; ++kb2) {
        uint X0 = (st2 ? d1 : d0)[4*kb2+0], X1 = (st2 ? d1 : d0)[4*kb2+1];
        uint Y0 = (st2 ? d1 : d0)[4*kb2+2], Y1 = (st2 ? d1 : d0)[4*kb2+3];
        asm("v_permlane32_swap_b32 %0, %1" : "+v"(X0), "+v"(Y0));
        asm("v_permlane32_swap_b32 %0, %1" : "+v"(X1), "+v"(Y1));
        uint4 u = {X0, X1, Y0, Y1};
        pf[st2*2+kb2] = __builtin_bit_cast(bf16x8, u);
      }

    // PV: D[c][t] += V[c][s] * P^T[s][t]; A-frag: m=c-row=l31, k=s=8hi+j
    const u16* vb_ = vbuf[buf];
    __builtin_amdgcn_s_setprio(1);
#pragma unroll
    for (int ks = 0; ks < 4; ++ks) {
      bf16x8 a0 = *(const bf16x8*)(vb_ + l31*64      + (((2*ks+hi) ^ (l31 & 7)) * 8));
      bf16x8 a1 = *(const bf16x8*)(vb_ + (32+l31)*64 + (((2*ks+hi) ^ (l31 & 7)) * 8));
      acc0 = __builtin_amdgcn_mfma_f32_32x32x16_bf16(a0, pf[ks], acc0, 0, 0, 0);
      acc1 = __builtin_amdgcn_mfma_f32_32x32x16_bf16(a1, pf[ks], acc1, 0, 0, 0);
    }
    __builtin_amdgcn_s_setprio(0);

    __syncthreads();   // all waves done with buf; prefetch into buf^1 landed
    buf ^= 1;
  }
#undef STAGE

  float linv = 1.0f / l_run;
  float* ob = out + (size_t)(bh*64) * SEQ + t0 + wave*32 + l31;
#pragma unroll
  for (int r = 0; r < 16; ++r) {
    int c0 = (r & 3) + 8*(r >> 2) + 4*hi;
    ob[(size_t)c0 * SEQ]        = acc0[r] * linv;
    ob[(size_t)(32 + c0) * SEQ] = acc1[r] * linv;
  }
}

extern "C" void kernel_launch(void* const* d_in, const int* in_sizes, int n_in,
                              void* d_out, int out_size, void* d_ws, size_t ws_size,
                              hipStream_t stream) {
  const float* qkv = (const float*)d_in[0];
  float* out = (float*)d_out;
  u16* qT = (u16*)d_ws;
  u16* kT = qT + (size_t)32*SEQ*DH;
  u16* vB = kT + (size_t)32*SEQ*DH;
  transpose_qk<<<2048, 256, 0, stream>>>(qkv, qT, kT);
  convert_v<<<2048, 256, 0, stream>>>(qkv, vB);
  attn<<<512, 256, 0, stream>>>(qT, kT, vB, out);
}